// Round 14
// baseline (309.205 us; speedup 1.0000x reference)
//
#include <hip/hip_runtime.h>

#define N_NODES 100000
#define E_EDGES 1600000
#define F_IN    128
#define H_DIM   64
#define C_OUT   16
#define L_LAYERS 3
#define NTOT    (E_EDGES + N_NODES)
#define MAXD    64    // LDS-staged degree cap in agg; fallback recomputes

#define BKN2    512
#define NB2     ((N_NODES + BKN2 - 1) / BKN2)         // 196
#define BCAP    9216
#define CH      8192
#define PB      ((E_EDGES + CH - 1) / CH)             // 196

typedef __attribute__((ext_vector_type(8))) short short8;
typedef __attribute__((ext_vector_type(4))) float f32x4;

// bf16 helpers
__device__ inline unsigned short f2bf(float f) {
    unsigned u = __float_as_uint(f);
    return (unsigned short)((u + 0x7FFFu + ((u >> 16) & 1u)) >> 16);
}
__device__ inline float bf_lo(unsigned p) { return __uint_as_float(p << 16); }
__device__ inline float bf_hi(unsigned p) { return __uint_as_float(p & 0xFFFF0000u); }
__device__ inline unsigned cvt_pk_bf16(float lo, float hi) {
    unsigned r;
    asm("v_cvt_pk_bf16_f32 %0, %1, %2" : "=v"(r) : "v"(lo), "v"(hi));
    return r;
}

// ---------------- pass B: block-local bucket sort + dense scatter ----------------
__global__ __launch_bounds__(256) void bucket_scatter2(
        const void* __restrict__ eidx,
        int* __restrict__ bcur, unsigned int* __restrict__ packed) {
    __shared__ int cnt[NB2], basel[NB2], curl[NB2], gbase[NB2];
    __shared__ int sd[256];
    __shared__ int sflag;
    __shared__ unsigned int stage[CH];
    __shared__ unsigned char bkt[CH];
    int t = threadIdx.x;
    int b0 = blockIdx.x * CH;
    int ne = min(CH, E_EDGES - b0);
    if (t == 0) sflag = 0;
    for (int i = t; i < NB2; i += 256) cnt[i] = 0;
    __syncthreads();
    {
        int nsamp = min(ne, 1024);
        int any = 0;
        for (int j = t; j < nsamp; j += 256)
            if (((const unsigned*)eidx)[2 * (size_t)(b0 + j) + 1] != 0u) any = 1;
        if (any) atomicOr(&sflag, 1);
    }
    __syncthreads();
    int f64 = sflag ? 0 : 1;

    int es[CH / 256], ed[CH / 256];
    #pragma unroll
    for (int j = 0; j < CH / 256; ++j) {
        int idx = b0 + j * 256 + t;
        if (idx < E_EDGES) {
            if (f64) {
                es[j] = (int)((const long long*)eidx)[idx];
                ed[j] = (int)((const long long*)eidx)[E_EDGES + idx];
            } else {
                es[j] = ((const int*)eidx)[idx];
                ed[j] = ((const int*)eidx)[E_EDGES + idx];
            }
            atomicAdd(&cnt[ed[j] >> 9], 1);
        } else { es[j] = -1; }
    }
    __syncthreads();
    int v = (t < NB2) ? cnt[t] : 0;
    sd[t] = v;
    __syncthreads();
    for (int off = 1; off < 256; off <<= 1) {
        int u = (t >= off) ? sd[t - off] : 0;
        __syncthreads();
        sd[t] += u;
        __syncthreads();
    }
    if (t < NB2) {
        basel[t] = sd[t] - v;
        curl[t] = 0;
        gbase[t] = atomicAdd(&bcur[t], v);
    }
    __syncthreads();
    #pragma unroll
    for (int j = 0; j < CH / 256; ++j) {
        if (es[j] >= 0) {
            int b = ed[j] >> 9;
            int r = atomicAdd(&curl[b], 1);
            int pos = basel[b] + r;
            stage[pos] = ((unsigned)(ed[j] & (BKN2 - 1)) << 17) | (unsigned)es[j];
            bkt[pos] = (unsigned char)b;
        }
    }
    __syncthreads();
    for (int i = t; i < ne; i += 256) {
        int b = bkt[i];
        packed[(size_t)b * BCAP + gbase[b] + (i - basel[b])] = stage[i];
    }
}

// ---------------- pass C: per-bucket CSR finalize (inline bucket prefix) ------
__global__ __launch_bounds__(256) void csr_build2(
        const unsigned int* __restrict__ packed, const int* __restrict__ bcur,
        int* __restrict__ row_ptr, int* __restrict__ csr_src) {
    __shared__ int cnt[BKN2], scn[BKN2], cur[BKN2];
    int b = blockIdx.x, t = threadIdx.x;
    scn[t] = (t < b) ? bcur[t] : 0;
    __syncthreads();
    for (int off = 128; off >= 1; off >>= 1) {
        if (t < off) scn[t] += scn[t + off];
        __syncthreads();
    }
    int ebase_b = scn[0];
    __syncthreads();

    int nbase = b * BKN2;
    int nn = min(BKN2, N_NODES - nbase);
    int ec = bcur[b];
    size_t pbase = (size_t)b * BCAP;
    int cbase = ebase_b + nbase;
    cnt[t] = (t < nn) ? 1 : 0;
    cnt[t + 256] = (t + 256 < nn) ? 1 : 0;
    __syncthreads();
    for (int i = t; i < ec; i += 256)
        atomicAdd(&cnt[packed[pbase + i] >> 17], 1);
    __syncthreads();
    scn[t] = cnt[t];
    scn[t + 256] = cnt[t + 256];
    __syncthreads();
    for (int off = 1; off < BKN2; off <<= 1) {
        int u0 = (t >= off) ? scn[t - off] : 0;
        int u1 = (t + 256 >= off) ? scn[t + 256 - off] : 0;
        __syncthreads();
        scn[t] += u0;
        scn[t + 256] += u1;
        __syncthreads();
    }
    #pragma unroll
    for (int q = 0; q < 2; ++q) {
        int idx = t + q * 256;
        if (idx < nn) {
            int offi = scn[idx] - cnt[idx];
            row_ptr[nbase + idx] = cbase + offi;
            csr_src[cbase + offi] = nbase + idx;   // self-loop first
            cur[idx] = offi + 1;
        }
    }
    if (b == NB2 - 1 && t == 0) row_ptr[N_NODES] = cbase + ec + nn;
    __syncthreads();
    for (int i = t; i < ec; i += 256) {
        unsigned p = packed[pbase + i];
        int dl = p >> 17, s = (int)(p & 0x1FFFFu);
        int pos = atomicAdd(&cur[dl], 1);
        csr_src[cbase + pos] = s;
    }
}

// ---------------- K0: fused input GEMM + layer-1 GEMM --------------------------
// x[64rows x 128] -> (MFMA1 w/ W_in, bias, leaky) -> h bf16 in LDS (per-wave
// transpose) -> (MFMA2 w/ Wc0^T) -> hw1 bf16 + as_/ad_.  h never hits memory.
#define SAW 136   // bf16 row stride, K=128 + pad8

__global__ __launch_bounds__(256) void k0_fused(
        const float* __restrict__ X, const float* __restrict__ Win,
        const float* __restrict__ bias, const float* __restrict__ Wc0,
        const float* __restrict__ asrc, const float* __restrict__ adst,
        unsigned* __restrict__ C, float* __restrict__ as_, float* __restrict__ ad_) {
    __shared__ __align__(16) unsigned char smem[54208];
    unsigned short (*sX)[SAW]   = (unsigned short(*)[SAW])smem;            // 64x136 bf16 = 17408
    unsigned short (*sWTin)[SAW]= (unsigned short(*)[SAW])(smem + 17408);  // 17408
    unsigned short (*sWT1)[72]  = (unsigned short(*)[72])(smem + 34816);   // 64x72 = 9216
    unsigned short (*sH)[72]    = (unsigned short(*)[72])(smem + 44032);   // 4x16x72 = 9216 (per-wave 16x72)
    float* sB  = (float*)(smem + 53248);                                   // 64
    float* sAv = sB + 64;
    float* sDv = sAv + 64;                                                 // end 53248+768=54016
    float* sTile = (float*)smem;   // aliases sX after barrier; 4*16*65*4 = 16640

    int t = threadIdx.x;
    int r0 = blockIdx.x * 64;
    // stage X -> bf16
    #pragma unroll
    for (int it = 0; it < 8; ++it) {
        int idx = it * 256 + t;
        int r = idx >> 5, c4 = (idx & 31) * 4;
        int gr = r0 + r;
        float4 v = make_float4(0.f, 0.f, 0.f, 0.f);
        if (gr < N_NODES) v = *(const float4*)&X[(size_t)gr * F_IN + c4];
        unsigned* dst = (unsigned*)&sX[r][c4];
        dst[0] = cvt_pk_bf16(v.x, v.y);
        dst[1] = cvt_pk_bf16(v.z, v.w);
    }
    // stage W_in^T -> bf16: Win[k][j] -> sWTin[j][k], k=0..127
    #pragma unroll
    for (int it = 0; it < 8; ++it) {
        int idx = it * 256 + t;
        int k = idx >> 4, j4 = (idx & 15) * 4;
        float4 v = *(const float4*)&Win[k * 64 + j4];
        sWTin[j4 + 0][k] = f2bf(v.x);
        sWTin[j4 + 1][k] = f2bf(v.y);
        sWTin[j4 + 2][k] = f2bf(v.z);
        sWTin[j4 + 3][k] = f2bf(v.w);
    }
    // stage Wc0^T -> bf16
    for (int i = t; i < 64 * 64; i += 256) {
        int k = i >> 6, j = i & 63;
        sWT1[j][k] = f2bf(Wc0[i]);
    }
    if (t < 64) { sB[t] = bias[t]; sAv[t] = asrc[t]; sDv[t] = adst[t]; }
    __syncthreads();

    int wave = t >> 6, lane = t & 63;
    int cj = lane & 15, kq = lane >> 4;
    int lrow = wave * 16 + cj;
    f32x4 zero = {0.f, 0.f, 0.f, 0.f};
    f32x4 acc[4] = {zero, zero, zero, zero};
    #pragma unroll
    for (int q = 0; q < 4; ++q) {
        short8 a = *(const short8*)&sX[lrow][q * 32 + kq * 8];
        #pragma unroll
        for (int ct = 0; ct < 4; ++ct) {
            short8 bfr = *(const short8*)&sWTin[ct * 16 + cj][q * 32 + kq * 8];
            acc[ct] = __builtin_amdgcn_mfma_f32_16x16x32_bf16(a, bfr, acc[ct], 0, 0, 0);
        }
    }
    // bias + leaky -> h bf16 into per-wave sH tile (transpose: C-layout -> row-major)
    unsigned short (*sHw)[72] = &sH[wave * 16];
    #pragma unroll
    for (int ct = 0; ct < 4; ++ct) {
        float bsv = sB[ct * 16 + cj];
        #pragma unroll
        for (int r = 0; r < 4; ++r) {
            float v = acc[ct][r] + bsv;
            v = v > 0.f ? v : 0.01f * v;
            sHw[kq * 4 + r][ct * 16 + cj] = f2bf(v);
        }
    }
    // MFMA2 (wave-local sH; compiler inserts lgkmcnt)
    short8 a0 = *(const short8*)&sHw[cj][kq * 8];
    short8 a1 = *(const short8*)&sHw[cj][32 + kq * 8];
    f32x4 acc2[4] = {zero, zero, zero, zero};
    #pragma unroll
    for (int ct = 0; ct < 4; ++ct) {
        short8 b0 = *(const short8*)&sWT1[16 * ct + cj][kq * 8];
        short8 b1 = *(const short8*)&sWT1[16 * ct + cj][32 + kq * 8];
        acc2[ct] = __builtin_amdgcn_mfma_f32_16x16x32_bf16(a0, b0, acc2[ct], 0, 0, 0);
        acc2[ct] = __builtin_amdgcn_mfma_f32_16x16x32_bf16(a1, b1, acc2[ct], 0, 0, 0);
    }
    // DOTS epilogue
    float av[4], dv[4];
    #pragma unroll
    for (int ct = 0; ct < 4; ++ct) { av[ct] = sAv[ct * 16 + cj]; dv[ct] = sDv[ct * 16 + cj]; }
    int wr0 = r0 + wave * 16;
    #pragma unroll
    for (int r = 0; r < 4; ++r) {
        float ds = acc2[0][r] * av[0] + acc2[1][r] * av[1] + acc2[2][r] * av[2] + acc2[3][r] * av[3];
        float dd = acc2[0][r] * dv[0] + acc2[1][r] * dv[1] + acc2[2][r] * dv[2] + acc2[3][r] * dv[3];
        #pragma unroll
        for (int off = 1; off < 16; off <<= 1) {
            ds += __shfl_xor(ds, off);
            dd += __shfl_xor(dd, off);
        }
        int grow = wr0 + kq * 4 + r;
        if (cj == 0 && grow < N_NODES) { as_[grow] = ds; ad_[grow] = dd; }
    }
    __syncthreads();   // all MFMA1/MFMA2 LDS reads done; sX region reusable
    float* tl = sTile + wave * (16 * 65);
    #pragma unroll
    for (int ct = 0; ct < 4; ++ct)
        #pragma unroll
        for (int r = 0; r < 4; ++r)
            tl[(kq * 4 + r) * 65 + ct * 16 + cj] = acc2[ct][r];
    unsigned ur[8];
    int trow = lane >> 2, tcb = lane & 3;
    #pragma unroll
    for (int i = 0; i < 8; ++i) {
        float2 fp = *(const float2*)&tl[trow * 65 + tcb * 16 + i * 2];
        ur[i] = cvt_pk_bf16(fp.x, fp.y);
    }
    int grow = wr0 + trow;
    if (grow < N_NODES) {
        uint4* dst = (uint4*)&C[(size_t)grow * 32 + tcb * 8];
        dst[0] = make_uint4(ur[0], ur[1], ur[2], ur[3]);
        dst[1] = make_uint4(ur[4], ur[5], ur[6], ur[7]);
    }
}

// ---------------- MFMA layer GEMM (unchanged from R13) ----------------
__global__ __launch_bounds__(256) void gemm_mfma_kernel(
        const unsigned* __restrict__ A32, const float* __restrict__ W,
        const float* __restrict__ asrc, const float* __restrict__ adst,
        unsigned* __restrict__ C, float* __restrict__ as_, float* __restrict__ ad_) {
    __shared__ __align__(16) unsigned short sWT[64][72];
    __shared__ float sAv[64], sDv[64];
    __shared__ __align__(16) float sTile[4][16 * 65];
    int t = threadIdx.x;
    for (int i = t; i < 64 * 64; i += 256) {
        int k = i >> 6, j = i & 63;
        sWT[j][k] = f2bf(W[i]);
    }
    if (t < 64) { sAv[t] = asrc[t]; sDv[t] = adst[t]; }
    __syncthreads();

    int wave = t >> 6, lane = t & 63;
    int r0 = blockIdx.x * 64 + wave * 16;
    int cj = lane & 15, kq = lane >> 4;

    int ra = r0 + cj;
    if (ra >= N_NODES) ra = N_NODES - 1;
    const short8* arow = (const short8*)&A32[(size_t)ra * 32];
    short8 a0 = arow[kq];
    short8 a1 = arow[4 + kq];

    f32x4 zero = {0.f, 0.f, 0.f, 0.f};
    f32x4 acc[4] = {zero, zero, zero, zero};
    #pragma unroll
    for (int ct = 0; ct < 4; ++ct) {
        short8 b0 = *(const short8*)&sWT[16 * ct + cj][kq * 8];
        short8 b1 = *(const short8*)&sWT[16 * ct + cj][32 + kq * 8];
        acc[ct] = __builtin_amdgcn_mfma_f32_16x16x32_bf16(a0, b0, acc[ct], 0, 0, 0);
        acc[ct] = __builtin_amdgcn_mfma_f32_16x16x32_bf16(a1, b1, acc[ct], 0, 0, 0);
    }

    float av[4], dv[4];
    #pragma unroll
    for (int ct = 0; ct < 4; ++ct) { av[ct] = sAv[ct * 16 + cj]; dv[ct] = sDv[ct * 16 + cj]; }
    #pragma unroll
    for (int r = 0; r < 4; ++r) {
        float ds = acc[0][r] * av[0] + acc[1][r] * av[1] + acc[2][r] * av[2] + acc[3][r] * av[3];
        float dd = acc[0][r] * dv[0] + acc[1][r] * dv[1] + acc[2][r] * dv[2] + acc[3][r] * dv[3];
        #pragma unroll
        for (int off = 1; off < 16; off <<= 1) {
            ds += __shfl_xor(ds, off);
            dd += __shfl_xor(dd, off);
        }
        int grow = r0 + kq * 4 + r;
        if (cj == 0 && grow < N_NODES) { as_[grow] = ds; ad_[grow] = dd; }
    }

    float* tl = sTile[wave];
    #pragma unroll
    for (int ct = 0; ct < 4; ++ct)
        #pragma unroll
        for (int r = 0; r < 4; ++r)
            tl[(kq * 4 + r) * 65 + ct * 16 + cj] = acc[ct][r];
    unsigned ur[8];
    int trow = lane >> 2, tcb = lane & 3;
    #pragma unroll
    for (int i = 0; i < 8; ++i) {
        float2 fp = *(const float2*)&tl[trow * 65 + tcb * 16 + i * 2];
        ur[i] = cvt_pk_bf16(fp.x, fp.y);
    }
    int grow = r0 + trow;
    if (grow < N_NODES) {
        uint4* dst = (uint4*)&C[(size_t)grow * 32 + tcb * 8];
        dst[0] = make_uint4(ur[0], ur[1], ur[2], ur[3]);
        dst[1] = make_uint4(ur[4], ur[5], ur[6], ur[7]);
    }
}

// ---------------- fused aggregation; FUSE_OUT adds out-GEMM + log_softmax ----
template<bool FUSE_OUT>
__global__ __launch_bounds__(256) void agg_kernel(
        const int* __restrict__ row_ptr, const int* __restrict__ csr_src,
        const float* __restrict__ as_, const float* __restrict__ ad_,
        const unsigned* __restrict__ hw32, const float* __restrict__ bc,
        unsigned* __restrict__ hout32,
        const float* __restrict__ Wo, const float* __restrict__ bo,
        float* __restrict__ out) {
    __shared__ float exbuf[4][MAXD];
    __shared__ int   sbuf[4][MAXD];
    __shared__ float sh[4][64];
    __shared__ float sWo[64 * 16];
    __shared__ float sbo[16];
    int wave = threadIdx.x >> 6, lane = threadIdx.x & 63;
    int t = threadIdx.x;
    if (FUSE_OUT) {
        for (int i = t; i < 64 * 16; i += 256) sWo[i] = Wo[i];
        if (t < 16) sbo[t] = bo[t];
        __syncthreads();
    }
    int node = blockIdx.x * 4 + wave;
    if (node >= N_NODES) return;
    int rs = row_ptr[node], re = row_ptr[node + 1];
    int deg = re - rs;
    float aD = ad_[node];
    float psum = 0.f;
    for (int i = lane; i < deg; i += 64) {
        int s = csr_src[rs + i];
        float v = as_[s] + aD;
        v = v > 0.f ? v : 0.2f * v;
        float p = __expf(v);
        if (deg <= MAXD) { exbuf[wave][i] = p; sbuf[wave][i] = s; }
        psum += p;
    }
    #pragma unroll
    for (int off = 32; off >= 1; off >>= 1) psum += __shfl_xor(psum, off);
    float inv = 1.f / (psum + 1e-16f);

    int g = lane >> 4, fl16 = lane & 15;
    float a0 = 0.f, a1 = 0.f, a2 = 0.f, a3 = 0.f;
    if (deg <= MAXD) {
        int i = g;
        for (; i + 12 < deg; i += 16) {
            float w0 = exbuf[wave][i],      w1 = exbuf[wave][i + 4];
            float w2 = exbuf[wave][i + 8],  w3 = exbuf[wave][i + 12];
            int s0 = sbuf[wave][i],     s1 = sbuf[wave][i + 4];
            int s2 = sbuf[wave][i + 8], s3 = sbuf[wave][i + 12];
            uint2 p0 = *(const uint2*)&hw32[((unsigned)s0 << 5) | (fl16 * 2)];
            uint2 p1 = *(const uint2*)&hw32[((unsigned)s1 << 5) | (fl16 * 2)];
            uint2 p2 = *(const uint2*)&hw32[((unsigned)s2 << 5) | (fl16 * 2)];
            uint2 p3 = *(const uint2*)&hw32[((unsigned)s3 << 5) | (fl16 * 2)];
            a0 += w0 * bf_lo(p0.x) + w1 * bf_lo(p1.x) + w2 * bf_lo(p2.x) + w3 * bf_lo(p3.x);
            a1 += w0 * bf_hi(p0.x) + w1 * bf_hi(p1.x) + w2 * bf_hi(p2.x) + w3 * bf_hi(p3.x);
            a2 += w0 * bf_lo(p0.y) + w1 * bf_lo(p1.y) + w2 * bf_lo(p2.y) + w3 * bf_lo(p3.y);
            a3 += w0 * bf_hi(p0.y) + w1 * bf_hi(p1.y) + w2 * bf_hi(p2.y) + w3 * bf_hi(p3.y);
        }
        for (; i < deg; i += 4) {
            float w = exbuf[wave][i];
            int s = sbuf[wave][i];
            uint2 p = *(const uint2*)&hw32[((unsigned)s << 5) | (fl16 * 2)];
            a0 += w * bf_lo(p.x);
            a1 += w * bf_hi(p.x);
            a2 += w * bf_lo(p.y);
            a3 += w * bf_hi(p.y);
        }
    } else {
        for (int i = g; i < deg; i += 4) {
            int s = csr_src[rs + i];
            float v = as_[s] + aD;
            v = v > 0.f ? v : 0.2f * v;
            float w = __expf(v);
            uint2 p = *(const uint2*)&hw32[((unsigned)s << 5) | (fl16 * 2)];
            a0 += w * bf_lo(p.x);
            a1 += w * bf_hi(p.x);
            a2 += w * bf_lo(p.y);
            a3 += w * bf_hi(p.y);
        }
    }
    a0 += __shfl_xor(a0, 16); a0 += __shfl_xor(a0, 32);
    a1 += __shfl_xor(a1, 16); a1 += __shfl_xor(a1, 32);
    a2 += __shfl_xor(a2, 16); a2 += __shfl_xor(a2, 32);
    a3 += __shfl_xor(a3, 16); a3 += __shfl_xor(a3, 32);
    if (g == 0) {
        float4 bv = *(const float4*)&bc[fl16 * 4];
        float v0 = a0 * inv + bv.x; v0 = v0 > 0.f ? v0 : 0.01f * v0;
        float v1 = a1 * inv + bv.y; v1 = v1 > 0.f ? v1 : 0.01f * v1;
        float v2 = a2 * inv + bv.z; v2 = v2 > 0.f ? v2 : 0.01f * v2;
        float v3 = a3 * inv + bv.w; v3 = v3 > 0.f ? v3 : 0.01f * v3;
        if (FUSE_OUT) {
            sh[wave][fl16 * 4 + 0] = v0;
            sh[wave][fl16 * 4 + 1] = v1;
            sh[wave][fl16 * 4 + 2] = v2;
            sh[wave][fl16 * 4 + 3] = v3;
        } else {
            *(uint2*)&hout32[((unsigned)node << 5) | (fl16 * 2)] =
                make_uint2(cvt_pk_bf16(v0, v1), cvt_pk_bf16(v2, v3));
        }
    }
    if (FUSE_OUT) {
        // lanes 0-15: logit c = fl16 (wave-local LDS; lgkmcnt ordering suffices)
        if (g == 0) {
            float acc = sbo[fl16];
            #pragma unroll 8
            for (int k = 0; k < 64; ++k) acc += sh[wave][k] * sWo[k * 16 + fl16];
            float m = acc;
            #pragma unroll
            for (int off = 8; off >= 1; off >>= 1) m = fmaxf(m, __shfl_xor(m, off, 16));
            float e = __expf(acc - m);
            float ssum = e;
            #pragma unroll
            for (int off = 8; off >= 1; off >>= 1) ssum += __shfl_xor(ssum, off, 16);
            out[(size_t)node * C_OUT + fl16] = acc - m - __logf(ssum);
        }
    }
}

extern "C" void kernel_launch(void* const* d_in, const int* in_sizes, int n_in,
                              void* d_out, int out_size, void* d_ws, size_t ws_size,
                              hipStream_t stream) {
    const float* x     = (const float*)d_in[0];
    const void*  eidx  = d_in[1];
    const float* W_in  = (const float*)d_in[3];
    const float* b_in  = (const float*)d_in[4];
    const float* Wc    = (const float*)d_in[5];
    const float* a_src = (const float*)d_in[6];
    const float* a_dst = (const float*)d_in[7];
    const float* bc    = (const float*)d_in[8];
    const float* W_out = (const float*)d_in[9];
    const float* b_out = (const float*)d_in[10];
    float* out = (float*)d_out;

    // workspace
    unsigned* h     = (unsigned*)d_ws;                     // N*32 uints
    unsigned* hw    = h + (size_t)N_NODES * 32;            // N*32 uints
    float* as_      = (float*)(hw + (size_t)N_NODES * 32); // N
    float* ad_      = as_ + N_NODES;                       // N
    int*   row_ptr  = (int*)(ad_ + N_NODES);               // N+1
    int*   csr_src  = row_ptr + N_NODES + 1;               // E+N
    unsigned int* packed = (unsigned int*)(csr_src + NTOT);// NB2*BCAP
    int*   bcur     = (int*)(packed + (size_t)NB2 * BCAP); // NB2

    hipMemsetAsync(bcur, 0, NB2 * sizeof(int), stream);
    bucket_scatter2<<<PB, 256, 0, stream>>>(eidx, bcur, packed);
    csr_build2<<<NB2, 256, 0, stream>>>(packed, bcur, row_ptr, csr_src);

    int mblocks = (N_NODES + 63) / 64;
    // K0: x -> h (LDS) -> hw(layer1) + as/ad
    k0_fused<<<mblocks, 256, 0, stream>>>(
        x, W_in, b_in, Wc, a_src, a_dst, hw, as_, ad_);

    int ablocks = (N_NODES + 3) / 4;
    // layer 1 agg -> h ; layer 2 gemm ; layer 2 agg -> h ; layer 3 gemm
    agg_kernel<false><<<ablocks, 256, 0, stream>>>(
        row_ptr, csr_src, as_, ad_, hw, bc + 0 * H_DIM, h,
        nullptr, nullptr, nullptr);
    gemm_mfma_kernel<<<mblocks, 256, 0, stream>>>(
        h, Wc + 1 * H_DIM * H_DIM, a_src + 1 * H_DIM, a_dst + 1 * H_DIM, hw, as_, ad_);
    agg_kernel<false><<<ablocks, 256, 0, stream>>>(
        row_ptr, csr_src, as_, ad_, hw, bc + 1 * H_DIM, h,
        nullptr, nullptr, nullptr);
    gemm_mfma_kernel<<<mblocks, 256, 0, stream>>>(
        h, Wc + 2 * H_DIM * H_DIM, a_src + 2 * H_DIM, a_dst + 2 * H_DIM, hw, as_, ad_);
    // K3: layer-3 agg fused with output GEMM + log_softmax
    agg_kernel<true><<<ablocks, 256, 0, stream>>>(
        row_ptr, csr_src, as_, ad_, hw, bc + 2 * H_DIM, nullptr,
        W_out, b_out, out);
}